// Round 5
// baseline (136.139 us; speedup 1.0000x reference)
//
#include <hip/hip_runtime.h>
#include <math.h>

#define NQ 12
#define DIM 4096
#define KS 6
#define BB 256
#define SEQ 128
#define DEMB 512

// v6 = v2 (1024 threads, 4 amps/thread, 16 waves -- R1-verified structure,
// 57us pre-pk) + v5's packed-FP32 SU(2) gates (R4-verified, -42% dispatch)
// + LDS footprint cut to 2x32KB: trip5 (E->F) swaps only wave-local
// addresses (wave field j[7:4] invariant), so it reuses buf0 in place;
// ring scatter uses buf1. 2 barriers/step unchanged.
//
// Layouts (j = 12-bit state index, wire w <-> bit 11-w):
//  L_A: r=j[1:0]   lane=j[7:2]            wave=j[11:8]
//  L_B: r=j[3:2]   lane={j[7:4],j[1:0]}   wave=j[11:8]
//  L_C: r=j[5:4]   lane={j[7:6],j[3:0]}   wave=j[11:8]
//  L_D: r=j[7:6]   lane=j[5:0]            wave=j[11:8]
//  L_E: r=j[9:8]   lane={j[11:10],j[3:0]} wave=j[7:4]
//  L_F: r=j[11:10] lane={j[9:8],j[3:0]}   wave=j[7:4]
// Trips: A->B,B->C,C->D intra-wave (buf0 + lgkmcnt fence); D->E cross-wave
// (buf0, B1); E->F intra-wave IN-PLACE (buf0, fence); ring-folded F->A'
// (buf1, B2). Expvals PRE-ring in L_F via prefix-XOR parities (R1-verified).

typedef float f2 __attribute__((ext_vector_type(2)));

// packed complex 2x2 SU(2) gate: U = [[E0+iE1, E2+iE3],[-E2+iE3, E0-iE1]]
#define RG(P, W) { \
    f2 E01 = *(const f2*)&s_u[k][W][0]; \
    f2 E23 = *(const f2*)&s_u[k][W][2]; \
    f2 PR0 = (f2){ E01.x,  E01.x}; \
    f2 PI0 = (f2){-E01.y,  E01.y}; \
    f2 PR1 = (f2){ E23.x,  E23.x}; \
    f2 PI1 = (f2){-E23.y,  E23.y}; \
    _Pragma("unroll") \
    for (int r0 = 0; r0 < 4; ++r0) if (!(r0 & (1 << (P)))) { \
        int r1 = r0 | (1 << (P)); \
        f2 A = a[r0], Bv = a[r1]; \
        f2 As = (f2){A.y, A.x}, Bs = (f2){Bv.y, Bv.x}; \
        a[r0] = PR0*A  + PI0*As + PR1*Bv + PI1*Bs; \
        a[r1] = PR0*Bv - PI0*Bs - PR1*A  + PI1*As; \
    } }

#define BF_PLAIN(v, m) { float p_ = __shfl_xor(v, m, 64); v = v + p_; }
#define BF_SIGN(v, m)  { float p_ = __shfl_xor(v, m, 64); float d_ = v - p_; \
                         v = (lane & m) ? -d_ : d_; }

// wave-local LDS write->read ordering (no block barrier)
#define WAVE_FENCE() asm volatile("s_waitcnt lgkmcnt(0)" ::: "memory")

__device__ __forceinline__ int swz14(int x) { return x ^ ((x >> 4) & 14); }

__global__ __launch_bounds__(1024) void fused_kernel(
    const int* __restrict__ ids, const int* __restrict__ mask,
    const float* __restrict__ emb, const float* __restrict__ pw,
    const float* __restrict__ pb, const float* __restrict__ theta,
    const float* __restrict__ hw, const float* __restrict__ hb,
    float* __restrict__ readouts, float* __restrict__ logits,
    float* __restrict__ last)
{
    __shared__ __align__(16) f2    buf0[DIM];   // 32 KB (trips A-F / enc partials)
    __shared__ __align__(16) f2    buf1[DIM];   // 32 KB (ring scatter / enc ids)
    __shared__ __align__(16) float s_u[KS][NQ][4];
    __shared__ float  s_red[16][NQ];
    __shared__ float  s_msum[8];
    __shared__ float  s_wred[2][NQ];
    __shared__ float  s_x[NQ];
    __shared__ float  s_hw[8 * NQ];
    __shared__ float  s_hb[8];

    int b = blockIdx.x;
    int tid = threadIdx.x;
    int lane = tid & 63, wave = tid >> 6;     // wave 0..15

    // ---------------- encoder (v2 verbatim, R1-verified) ----------------
    int*   s_ids = (int*)buf1;
    float* s_m   = (float*)buf1 + SEQ;
    float4* s_part = (float4*)buf0;           // [8][128]

    if (tid < SEQ) {
        s_ids[tid] = ids[b * SEQ + tid];
        s_m[tid]   = (float)mask[b * SEQ + tid];
    }
    if (tid >= 256 && tid < 256 + 8 * NQ) s_hw[tid - 256] = hw[tid - 256];
    if (tid >= 384 && tid < 392)          s_hb[tid - 384] = hb[tid - 384];
    __syncthreads();

    {
        int g = tid >> 7, e = tid & 127;      // g 0..7
        float4 acc = make_float4(0.f, 0.f, 0.f, 0.f);
        float msum = 0.f;
        #pragma unroll 4
        for (int s = g; s < SEQ; s += 8) {
            float m = s_m[s];
            float4 v = ((const float4*)emb)[(size_t)s_ids[s] * 128 + e];
            acc.x = fmaf(m, v.x, acc.x);
            acc.y = fmaf(m, v.y, acc.y);
            acc.z = fmaf(m, v.z, acc.z);
            acc.w = fmaf(m, v.w, acc.w);
            msum += m;
        }
        __syncthreads();   // all s_ids/s_m reads complete
        s_part[g * 128 + e] = acc;
        if (e == 0) s_msum[g] = msum;
    }
    __syncthreads();

    if (tid < 128) {
        float tm = s_msum[0] + s_msum[1] + s_msum[2] + s_msum[3]
                 + s_msum[4] + s_msum[5] + s_msum[6] + s_msum[7];
        tm = fmaxf(tm, 1.f);
        float inv = 1.f / tm;
        float4 p = make_float4(0.f, 0.f, 0.f, 0.f);
        #pragma unroll
        for (int g = 0; g < 8; ++g) {
            float4 pg = s_part[g * 128 + tid];
            p.x += pg.x; p.y += pg.y; p.z += pg.z; p.w += pg.w;
        }
        p.x *= inv; p.y *= inv; p.z *= inv; p.w *= inv;
        float z[NQ];
        #pragma unroll
        for (int i = 0; i < NQ; ++i) {
            float4 w4 = ((const float4*)pw)[i * 128 + tid];
            z[i] = p.x * w4.x + p.y * w4.y + p.z * w4.z + p.w * w4.w;
        }
        #pragma unroll
        for (int i = 0; i < NQ; ++i) {
            #pragma unroll
            for (int off = 32; off > 0; off >>= 1)
                z[i] += __shfl_xor(z[i], off, 64);
        }
        if ((tid & 63) == 0) {
            int w = tid >> 6;
            #pragma unroll
            for (int i = 0; i < NQ; ++i) s_wred[w][i] = z[i];
        }
    }
    __syncthreads();
    if (tid < NQ) {
        float d = pb[tid] + s_wred[0][tid] + s_wred[1][tid];
        s_x[tid] = tanhf(d) * 3.14159274101257324f;
    }
    __syncthreads();

    // ------ gate matrices: U = Rot(phi,te,om) @ RY(x), SU(2)-compressed ---
    // (R2/R4-verified) E0..E3; U = [[E0+iE1, E2+iE3],[-E2+iE3, E0-iE1]]
    if (tid < KS * NQ * 4) {
        int k = tid / 48;
        int rem = tid - k * 48;
        int w = rem >> 2, q = rem & 3;
        float ang = s_x[w];
        float cy = cosf(0.5f * ang), sy = sinf(0.5f * ang);
        const float* th = theta + (k * NQ + w) * 3;
        float phi = th[0], te = th[1], om = th[2];
        float ct = cosf(0.5f * te), st = sinf(0.5f * te);
        float a1 = -0.5f * (phi + om);
        float a2 =  0.5f * (phi - om);
        float ar =  cosf(a1) * ct, ai =  sinf(a1) * ct;   // R00
        float br = -cosf(a2) * st, bi = -sinf(a2) * st;   // R01
        float x1 = (q & 1) ? ai : ar;
        float x2 = (q & 1) ? bi : br;
        float E  = (q & 2) ? (x2 * cy - x1 * sy) : (x1 * cy + x2 * sy);
        s_u[k][w][q] = E;
    }

    // ---------------- constant addresses (v2 verbatim) ----------------
    int T4 = tid << 2;                 // L_A base logical index (4 amps)
    int bA4 = swz14(T4) >> 1;          // float4 idx; partner at bA4^1
    int aB[4], aC[4], aD[4], aE[4], aF[4], idxP[4];
    #pragma unroll
    for (int r = 0; r < 4; ++r) {
        aB[r] = swz14((wave << 8) | ((lane >> 2) << 4) | (r << 2) | (lane & 3));
        aC[r] = swz14((wave << 8) | ((lane >> 4) << 6) | (r << 4) | (lane & 15));
        aD[r] = swz14((wave << 8) | (r << 6) | lane);
        aE[r] = swz14(((lane >> 4) << 10) | (r << 8) | (wave << 4) | (lane & 15));
        int jF = (r << 10) | ((lane >> 4) << 8) | (wave << 4) | (lane & 15);
        aF[r] = swz14(jF);
        // ring CNOT permutation (prefix-XOR), harness-verified
        int b0 = (jF >> 11) & 1;
        int pref = b0, outv = 0;
        for (int w = 1; w < NQ; ++w) {
            pref ^= (jF >> (11 - w)) & 1;
            outv |= pref << (11 - w);
        }
        outv |= (b0 ^ pref) << 11;
        idxP[r] = swz14(outv);
    }
    // wave-bit (j[7:4]) sign parities for expvals
    int s3v   = (wave >> 3) & 1;               // j[7]   (wire 4)
    int s32v  = s3v ^ ((wave >> 2) & 1);       // j[7:6]
    int s321v = s32v ^ ((wave >> 1) & 1);      // j[7:5]
    int sallv = s321v ^ (wave & 1);            // j[7:4]

    f2 a[4];
    #pragma unroll
    for (int r = 0; r < 4; ++r) a[r] = (f2){0.f, 0.f};
    if (tid == 0) a[0].x = 1.f;     // |0...0>: j=0 -> wave0,lane0,r0
    __syncthreads();   // s_u ready, enc buf reads done

    // ---------------- K steps ----------------
    for (int k = 0; k < KS; ++k) {
        // phase A (L_A): wires 11,10
        RG(0, 11) RG(1, 10)

        // trip 1 (intra-wave): b128 dump -> gather L_B
        #pragma unroll
        for (int i = 0; i < 2; ++i)
            ((float4*)buf0)[bA4 ^ i] =
                make_float4(a[2*i].x, a[2*i].y, a[2*i+1].x, a[2*i+1].y);
        WAVE_FENCE();
        #pragma unroll
        for (int r = 0; r < 4; ++r) a[r] = buf0[aB[r]];

        // phase B (L_B): wires 9,8
        RG(0, 9) RG(1, 8)

        // trip 2 (intra-wave): dump L_B -> gather L_C
        #pragma unroll
        for (int r = 0; r < 4; ++r) buf0[aB[r]] = a[r];
        WAVE_FENCE();
        #pragma unroll
        for (int r = 0; r < 4; ++r) a[r] = buf0[aC[r]];

        // phase C (L_C): wires 7,6
        RG(0, 7) RG(1, 6)

        // trip 3 (intra-wave): dump L_C -> gather L_D
        #pragma unroll
        for (int r = 0; r < 4; ++r) buf0[aC[r]] = a[r];
        WAVE_FENCE();
        #pragma unroll
        for (int r = 0; r < 4; ++r) a[r] = buf0[aD[r]];

        // phase D (L_D): wires 5,4
        RG(0, 5) RG(1, 4)

        // trip 4 (cross-wave): dump L_D -> barrier -> gather L_E
        #pragma unroll
        for (int r = 0; r < 4; ++r) buf0[aD[r]] = a[r];
        __syncthreads();                                   // B1
        #pragma unroll
        for (int r = 0; r < 4; ++r) a[r] = buf0[aE[r]];

        // phase E (L_E): wires 3,2
        RG(0, 3) RG(1, 2)

        // trip 5 (intra-wave, IN-PLACE in buf0): E<->F touches only
        // wave-local addresses (j[7:4] fixed) -> no cross-wave hazard.
        #pragma unroll
        for (int r = 0; r < 4; ++r) buf0[aE[r]] = a[r];
        WAVE_FENCE();
        #pragma unroll
        for (int r = 0; r < 4; ++r) a[r] = buf0[aF[r]];

        // phase F (L_F): wires 1,0
        RG(0, 1) RG(1, 0)

        // ring scatter FIRST (drains while expvals shuffle), into buf1
        #pragma unroll
        for (int r = 0; r < 4; ++r) buf1[idxP[r]] = a[r];

        // expvals PRE-ring in L_F (R1-verified): in-thread over r=j[11:10];
        // lane signs l5..l0 = j9,j8,j3..j0; wave signs j[7:4] at s_red write.
        {
            float p0 = a[0].x*a[0].x + a[0].y*a[0].y;
            float p1 = a[1].x*a[1].x + a[1].y*a[1].y;
            float p2 = a[2].x*a[2].x + a[2].y*a[2].y;
            float p3 = a[3].x*a[3].x + a[3].y*a[3].y;
            float T1v = (p0 + p3) - (p1 + p2);   // (-1)^(j11^j10)
            float T0v = (p0 + p2) - (p1 + p3);   // (-1)^(j10)

            float v1 = T1v;                       // wire 1: parity j[11:10]
            BF_PLAIN(v1,32) BF_PLAIN(v1,16) BF_PLAIN(v1,8)
            BF_PLAIN(v1,4)  BF_PLAIN(v1,2)  BF_PLAIN(v1,1)

            float c = T1v;
            BF_SIGN(c,32);                        // +j[9]
            float w2v = c; BF_PLAIN(w2v,16) BF_PLAIN(w2v,8) BF_PLAIN(w2v,4)
                           BF_PLAIN(w2v,2)  BF_PLAIN(w2v,1)
            BF_SIGN(c,16);                        // +j[8]
            float w3v = c; BF_PLAIN(w3v,8) BF_PLAIN(w3v,4)
                           BF_PLAIN(w3v,2) BF_PLAIN(w3v,1)
            BF_SIGN(c,8);                         // +j[3]
            float w8v = c; BF_PLAIN(w8v,4) BF_PLAIN(w8v,2) BF_PLAIN(w8v,1)
            BF_SIGN(c,4);                         // +j[2]
            float w9v = c; BF_PLAIN(w9v,2) BF_PLAIN(w9v,1)
            BF_SIGN(c,2);                         // +j[1]
            float w10v = c; BF_PLAIN(w10v,1)
            BF_SIGN(c,1);                         // +j[0]

            float q0 = T0v;                       // wire 0: parity j[10:0]
            BF_SIGN(q0,32) BF_SIGN(q0,16) BF_SIGN(q0,8)
            BF_SIGN(q0,4)  BF_SIGN(q0,2)  BF_SIGN(q0,1)

            if (lane == 0) {
                float* sr = s_red[wave];
                sr[0]  = sallv ? -q0   : q0;
                sr[1]  = v1;
                sr[2]  = w2v;
                sr[3]  = w3v;
                sr[4]  = s3v   ? -w3v  : w3v;
                sr[5]  = s32v  ? -w3v  : w3v;
                sr[6]  = s321v ? -w3v  : w3v;
                sr[7]  = sallv ? -w3v  : w3v;
                sr[8]  = sallv ? -w8v  : w8v;
                sr[9]  = sallv ? -w9v  : w9v;
                sr[10] = sallv ? -w10v : w10v;
                sr[11] = sallv ? -c    : c;
            }
        }

        __syncthreads();                                   // B2
        #pragma unroll
        for (int i = 0; i < 2; ++i) {
            float4 v = ((float4*)buf1)[bA4 ^ i];
            a[2*i]   = (f2){v.x, v.y};
            a[2*i+1] = (f2){v.z, v.w};
        }

        // finalize readouts + head (overlaps next step's phase-A gates)
        if (tid < NQ) {
            float s = 0.f;
            #pragma unroll
            for (int w2 = 0; w2 < 16; ++w2) s += s_red[w2][tid];
            readouts[(k * BB + b) * NQ + tid] = s;
        }
        if (tid < 8) {
            float acc2 = s_hb[tid];
            #pragma unroll
            for (int i = 0; i < NQ; ++i) {
                float si = 0.f;
                #pragma unroll
                for (int w2 = 0; w2 < 16; ++w2) si += s_red[w2][i];
                acc2 = fmaf(si, s_hw[tid * NQ + i], acc2);
            }
            logits[(k * BB + b) * 8 + tid] = acc2;
            if (k == KS - 1) last[b * 8 + tid] = acc2;
        }
    }
}

extern "C" void kernel_launch(void* const* d_in, const int* in_sizes, int n_in,
                              void* d_out, int out_size, void* d_ws, size_t ws_size,
                              hipStream_t stream) {
    const int*   ids   = (const int*)d_in[0];
    const int*   mask  = (const int*)d_in[1];
    const float* emb   = (const float*)d_in[2];
    const float* pw    = (const float*)d_in[3];
    const float* pb    = (const float*)d_in[4];
    const float* theta = (const float*)d_in[5];
    const float* hw    = (const float*)d_in[6];
    const float* hb    = (const float*)d_in[7];
    float* out = (float*)d_out;

    float* readouts = out + KS * BB * 8;              // [K,B,NQ]
    float* last     = out + KS * BB * 8 + KS * BB * NQ;

    fused_kernel<<<BB, 1024, 0, stream>>>(ids, mask, emb, pw, pb, theta,
                                          hw, hb, readouts, out, last);
}

// Round 6
// 129.671 us; speedup vs baseline: 1.0499x; 1.0499x over previous
//
#include <hip/hip_runtime.h>
#include <math.h>

#define NQ 12
#define DIM 4096
#define KS 6
#define BB 256
#define SEQ 128
#define DEMB 512

// v7 = v5 (best: 43.8us dispatch / 130.5 harness) + epilogue restructure:
//  - NO global stores inside the K loop: per-step expvals reduce into
//    s_rall[KS][NQ] (LDS, 288B); readouts/logits/last stored once post-loop.
//  - in-loop barriers are lgkmcnt-only (s_waitcnt lgkmcnt(0) + s_barrier):
//    __syncthreads' vmcnt(0) drain made every barrier wait on wave-0's
//    in-flight HBM stores (~500-900cy each, 12 barriers/dispatch).
// All gate math / layouts / trips / expvals / addressing are v5-verbatim
// (harness-verified R4). R5 post-mortem: 1024t+pk regressed (47.0 vs 43.8)
// -- post-pk the trip/barrier chain dominates, so the 4-trip 512t structure
// stands.
//
// Layouts (j = 12-bit state index, wire w <-> bit 11-w):
//   L_A: reg=bits0-2 (wires 11,10,9), lane=3-8, wave=9-11
//   L_B: reg=3-5 (8,7,6), lane=(0,1,2,6,7,8), wave=9-11
//   L_C: reg=6-8 (5,4,3), lane=0-5, wave=9-11
//   L_D: reg=9-11 (2,1,0), lane=0-5, wave=6-8
// Trips 1-2 intra-wave (buf0 + lgkmcnt fence); trip 3 cross-wave (B1);
// trip 4 = ring-folded scatter (buf1, B2). Expvals pre-ring via Walsh.

typedef float f2 __attribute__((ext_vector_type(2)));

// packed complex 2x2 SU(2) gate: U = [[E0+iE1, E2+iE3],[-E2+iE3, E0-iE1]]
#define RG(P, W) { \
    f2 E01 = *(const f2*)&s_u[k][W][0]; \
    f2 E23 = *(const f2*)&s_u[k][W][2]; \
    f2 PR0 = (f2){ E01.x,  E01.x}; \
    f2 PI0 = (f2){-E01.y,  E01.y}; \
    f2 PR1 = (f2){ E23.x,  E23.x}; \
    f2 PI1 = (f2){-E23.y,  E23.y}; \
    _Pragma("unroll") \
    for (int r0 = 0; r0 < 8; ++r0) if (!(r0 & (1 << (P)))) { \
        int r1 = r0 | (1 << (P)); \
        f2 A = a[r0], Bv = a[r1]; \
        f2 As = (f2){A.y, A.x}, Bs = (f2){Bv.y, Bv.x}; \
        a[r0] = PR0*A  + PI0*As + PR1*Bv + PI1*Bs; \
        a[r1] = PR0*Bv - PI0*Bs - PR1*A  + PI1*As; \
    } }

#define BF_PLAIN(v, m) { float p_ = __shfl_xor(v, m, 64); v = v + p_; }
#define BF_SIGN(v, m)  { float p_ = __shfl_xor(v, m, 64); float d_ = v - p_; \
                         v = (lane & m) ? -d_ : d_; }

// wave-local LDS write->read ordering (no block barrier)
#define WAVE_FENCE() asm volatile("s_waitcnt lgkmcnt(0)" ::: "memory")

// block barrier without vmcnt drain (no VMEM ops in the K loop)
#define BARRIER() { asm volatile("s_waitcnt lgkmcnt(0)" ::: "memory"); \
                    __builtin_amdgcn_s_barrier(); }

__device__ __forceinline__ int swz14(int x) { return x ^ ((x >> 4) & 14); }

__global__ __launch_bounds__(512) void fused_kernel(
    const int* __restrict__ ids, const int* __restrict__ mask,
    const float* __restrict__ emb, const float* __restrict__ pw,
    const float* __restrict__ pb, const float* __restrict__ theta,
    const float* __restrict__ hw, const float* __restrict__ hb,
    float* __restrict__ readouts, float* __restrict__ logits,
    float* __restrict__ last)
{
    __shared__ __align__(16) f2    buf0[DIM];   // 32 KB (trips 1-3)
    __shared__ __align__(16) f2    buf1[DIM];   // 32 KB (trip 4 / enc)
    __shared__ __align__(16) float s_u[KS][NQ][4];
    __shared__ float  s_red[8][NQ];
    __shared__ float  s_rall[KS][NQ];
    __shared__ float  s_msum[4];
    __shared__ float  s_wred[2][NQ];
    __shared__ float  s_x[NQ];
    __shared__ float  s_hw[8 * NQ];
    __shared__ float  s_hb[8];

    int b = blockIdx.x;
    int tid = threadIdx.x;
    int lane = tid & 63, wave = tid >> 6;     // wave 0..7

    // ---------------- encoder (v1 verbatim) ----------------
    int*   s_ids = (int*)buf1;
    float* s_m   = (float*)buf1 + SEQ;
    float4* s_part = (float4*)buf0;           // [4][128]

    if (tid < SEQ) {
        s_ids[tid] = ids[b * SEQ + tid];
        s_m[tid]   = (float)mask[b * SEQ + tid];
    }
    if (tid >= 256 && tid < 256 + 8 * NQ) s_hw[tid - 256] = hw[tid - 256];
    if (tid >= 384 && tid < 392)          s_hb[tid - 384] = hb[tid - 384];
    __syncthreads();

    {
        int g = tid >> 7, e = tid & 127;
        float4 acc = make_float4(0.f, 0.f, 0.f, 0.f);
        float msum = 0.f;
        #pragma unroll 4
        for (int s = g; s < SEQ; s += 4) {
            float m = s_m[s];
            float4 v = ((const float4*)emb)[(size_t)s_ids[s] * 128 + e];
            acc.x = fmaf(m, v.x, acc.x);
            acc.y = fmaf(m, v.y, acc.y);
            acc.z = fmaf(m, v.z, acc.z);
            acc.w = fmaf(m, v.w, acc.w);
            msum += m;
        }
        __syncthreads();   // ids/m reads done before buf0 overlay write
        s_part[g * 128 + e] = acc;
        if (e == 0) s_msum[g] = msum;
    }
    __syncthreads();

    if (tid < 128) {
        float tm = fmaxf(s_msum[0] + s_msum[1] + s_msum[2] + s_msum[3], 1.f);
        float inv = 1.f / tm;
        float4 p0 = s_part[0 * 128 + tid], p1 = s_part[1 * 128 + tid];
        float4 p2 = s_part[2 * 128 + tid], p3 = s_part[3 * 128 + tid];
        float4 p;
        p.x = (p0.x + p1.x + p2.x + p3.x) * inv;
        p.y = (p0.y + p1.y + p2.y + p3.y) * inv;
        p.z = (p0.z + p1.z + p2.z + p3.z) * inv;
        p.w = (p0.w + p1.w + p2.w + p3.w) * inv;
        float z[NQ];
        #pragma unroll
        for (int i = 0; i < NQ; ++i) {
            float4 w4 = ((const float4*)pw)[i * 128 + tid];
            z[i] = p.x * w4.x + p.y * w4.y + p.z * w4.z + p.w * w4.w;
        }
        #pragma unroll
        for (int i = 0; i < NQ; ++i) {
            #pragma unroll
            for (int off = 32; off > 0; off >>= 1)
                z[i] += __shfl_xor(z[i], off, 64);
        }
        if ((tid & 63) == 0) {
            int w = tid >> 6;
            #pragma unroll
            for (int i = 0; i < NQ; ++i) s_wred[w][i] = z[i];
        }
    }
    __syncthreads();
    if (tid < NQ) {
        float d = pb[tid] + s_wred[0][tid] + s_wred[1][tid];
        s_x[tid] = tanhf(d) * 3.14159274101257324f;
    }
    __syncthreads();

    // ------ gate matrices: U = Rot(phi,te,om) @ RY(x), SU(2)-compressed ---
    // (harness-verified R2/R4) E0..E3; U = [[E0+iE1, E2+iE3],[-E2+iE3, E0-iE1]]
    if (tid < KS * NQ * 4) {
        int k = tid / 48;
        int rem = tid - k * 48;
        int w = rem >> 2, q = rem & 3;
        float ang = s_x[w];
        float cy = cosf(0.5f * ang), sy = sinf(0.5f * ang);
        const float* th = theta + (k * NQ + w) * 3;
        float phi = th[0], te = th[1], om = th[2];
        float ct = cosf(0.5f * te), st = sinf(0.5f * te);
        float a1 = -0.5f * (phi + om);
        float a2 =  0.5f * (phi - om);
        float ar =  cosf(a1) * ct, ai =  sinf(a1) * ct;   // R00
        float br = -cosf(a2) * st, bi = -sinf(a2) * st;   // R01
        float x1 = (q & 1) ? ai : ar;
        float x2 = (q & 1) ? bi : br;
        float E  = (q & 2) ? (x2 * cy - x1 * sy) : (x1 * cy + x2 * sy);
        s_u[k][w][q] = E;
    }

    // ---------------- constant addresses ----------------
    int T8 = tid << 3;
    int baseA  = swz14(T8);
    int baseA4 = baseA >> 1;          // float4 index; elem i at baseA4^i
    int addrB[8], addrC[8], addrD[8], idxP[8];
    #pragma unroll
    for (int r = 0; r < 8; ++r) {
        addrB[r] = swz14((lane & 7) + 8 * r + 64 * (lane >> 3) + 512 * wave);
        addrC[r] = swz14(lane + 64 * r + 512 * wave);
        int jD   = lane + 64 * wave + 512 * r;
        addrD[r] = swz14(jD);
        int b0 = (jD >> 11) & 1;
        int pref = b0, outv = 0;
        for (int w = 1; w < NQ; ++w) {
            pref ^= (jD >> (11 - w)) & 1;
            outv |= pref << (11 - w);
        }
        outv |= (b0 ^ pref) << 11;
        idxP[r] = swz14(outv);
    }
    int w0b = wave & 1, w1b = (wave >> 1) & 1, w2b = (wave >> 2) & 1;
    int wall = w0b ^ w1b ^ w2b;

    f2 a[8];
    #pragma unroll
    for (int r = 0; r < 8; ++r) a[r] = (f2){0.f, 0.f};
    if (tid == 0) a[0].x = 1.f;
    __syncthreads();   // s_u ready, enc buf reads done

    // ---------------- K steps ----------------
    for (int k = 0; k < KS; ++k) {
        // phase 1 (L_A): wires 11,10,9
        RG(0, 11) RG(1, 10) RG(2, 9)

        // trip 1 (intra-wave): b128 dump -> gather L_B
        #pragma unroll
        for (int i = 0; i < 4; ++i)
            ((float4*)buf0)[baseA4 ^ i] =
                make_float4(a[2*i].x, a[2*i].y, a[2*i+1].x, a[2*i+1].y);
        WAVE_FENCE();
        #pragma unroll
        for (int r = 0; r < 8; ++r) a[r] = buf0[addrB[r]];

        // phase 2 (L_B): wires 8,7,6
        RG(0, 8) RG(1, 7) RG(2, 6)

        // trip 2 (intra-wave): dump L_B -> gather L_C
        #pragma unroll
        for (int r = 0; r < 8; ++r) buf0[addrB[r]] = a[r];
        WAVE_FENCE();
        #pragma unroll
        for (int r = 0; r < 8; ++r) a[r] = buf0[addrC[r]];

        // phase 3 (L_C): wires 5,4,3
        RG(0, 5) RG(1, 4) RG(2, 3)

        // trip 3 (cross-wave): dump L_C -> barrier -> gather L_D
        #pragma unroll
        for (int r = 0; r < 8; ++r) buf0[addrC[r]] = a[r];
        BARRIER();                                         // B1 (lgkm-only)
        #pragma unroll
        for (int r = 0; r < 8; ++r) a[r] = buf0[addrD[r]];

        // phase 4 (L_D): wires 2,1,0
        RG(0, 2) RG(1, 1) RG(2, 0)

        // trip 4: issue ring scatter FIRST (drains while expvals shuffle)
        #pragma unroll
        for (int r = 0; r < 8; ++r) buf1[idxP[r]] = a[r];

        // expvals PRE-ring (L_D Walsh; v1-verbatim, verified)
        {
            float p[8];
            #pragma unroll
            for (int r = 0; r < 8; ++r)
                p[r] = a[r].x * a[r].x + a[r].y * a[r].y;
            float Q1 = (p[0]+p[1]+p[6]+p[7]) - (p[2]+p[3]+p[4]+p[5]);
            float Q2 = (p[0]+p[3]+p[5]+p[6]) - (p[1]+p[2]+p[4]+p[7]);
            float Q0 = (p[0]+p[3]+p[4]+p[7]) - (p[1]+p[2]+p[5]+p[6]);
            float q1 = Q1, q2p = Q2, q0 = Q0;
            BF_PLAIN(q1,32) BF_PLAIN(q1,16) BF_PLAIN(q1,8)
            BF_PLAIN(q1,4)  BF_PLAIN(q1,2)  BF_PLAIN(q1,1)
            BF_PLAIN(q2p,32) BF_PLAIN(q2p,16) BF_PLAIN(q2p,8)
            BF_PLAIN(q2p,4)  BF_PLAIN(q2p,2)  BF_PLAIN(q2p,1)
            BF_SIGN(q0,32) BF_SIGN(q0,16) BF_SIGN(q0,8)
            BF_SIGN(q0,4)  BF_SIGN(q0,2)  BF_SIGN(q0,1)
            float c = Q2;
            BF_SIGN(c,32);
            float w6v = c; BF_PLAIN(w6v,16) BF_PLAIN(w6v,8) BF_PLAIN(w6v,4)
                           BF_PLAIN(w6v,2)  BF_PLAIN(w6v,1)
            BF_SIGN(c,16);
            float w7v = c; BF_PLAIN(w7v,8) BF_PLAIN(w7v,4)
                           BF_PLAIN(w7v,2) BF_PLAIN(w7v,1)
            BF_SIGN(c,8);
            float w8v = c; BF_PLAIN(w8v,4) BF_PLAIN(w8v,2) BF_PLAIN(w8v,1)
            BF_SIGN(c,4);
            float w9v = c; BF_PLAIN(w9v,2) BF_PLAIN(w9v,1)
            BF_SIGN(c,2);
            float w10v = c; BF_PLAIN(w10v,1)
            BF_SIGN(c,1);
            if (lane == 0) {
                float* sr = s_red[wave];
                sr[0]  = wall ? -q0  : q0;
                sr[1]  = q1;
                sr[2]  = q2p;
                sr[3]  = w2b ? -q2p : q2p;
                sr[4]  = (w1b ^ w2b) ? -q2p : q2p;
                sr[5]  = wall ? -q2p : q2p;
                sr[6]  = wall ? -w6v : w6v;
                sr[7]  = wall ? -w7v : w7v;
                sr[8]  = wall ? -w8v : w8v;
                sr[9]  = wall ? -w9v : w9v;
                sr[10] = wall ? -w10v : w10v;
                sr[11] = wall ? -c   : c;
            }
        }

        BARRIER();                                         // B2 (lgkm-only)
        #pragma unroll
        for (int i = 0; i < 4; ++i) {
            float4 v = ((float4*)buf1)[baseA4 ^ i];
            a[2*i]   = (f2){v.x, v.y};
            a[2*i+1] = (f2){v.z, v.w};
        }

        // per-step wave-sum only (no global stores in the loop; safe: next
        // s_red overwrite happens after next step's B1)
        if (tid < NQ) {
            float s = 0.f;
            #pragma unroll
            for (int w2 = 0; w2 < 8; ++w2) s += s_red[w2][tid];
            s_rall[k][tid] = s;
        }
    }

    // ---------------- epilogue: all global stores once ----------------
    BARRIER();   // s_rall complete, visible to all waves
    if (tid < KS * NQ) {                       // 72 threads: readouts
        int k = tid / NQ, i = tid - k * NQ;
        readouts[(k * BB + b) * NQ + i] = s_rall[k][i];
    }
    if (tid >= 128 && tid < 128 + KS * 8) {    // wave 2: logits + last
        int t = tid - 128;
        int k = t >> 3, c = t & 7;
        float acc2 = s_hb[c];
        #pragma unroll
        for (int i = 0; i < NQ; ++i)
            acc2 = fmaf(s_rall[k][i], s_hw[c * NQ + i], acc2);
        logits[(k * BB + b) * 8 + c] = acc2;
        if (k == KS - 1) last[b * 8 + c] = acc2;
    }
}

extern "C" void kernel_launch(void* const* d_in, const int* in_sizes, int n_in,
                              void* d_out, int out_size, void* d_ws, size_t ws_size,
                              hipStream_t stream) {
    const int*   ids   = (const int*)d_in[0];
    const int*   mask  = (const int*)d_in[1];
    const float* emb   = (const float*)d_in[2];
    const float* pw    = (const float*)d_in[3];
    const float* pb    = (const float*)d_in[4];
    const float* theta = (const float*)d_in[5];
    const float* hw    = (const float*)d_in[6];
    const float* hb    = (const float*)d_in[7];
    float* out = (float*)d_out;

    float* readouts = out + KS * BB * 8;              // [K,B,NQ]
    float* last     = out + KS * BB * 8 + KS * BB * NQ;

    fused_kernel<<<BB, 512, 0, stream>>>(ids, mask, emb, pw, pb, theta,
                                         hw, hb, readouts, out, last);
}

// Round 7
// 126.109 us; speedup vs baseline: 1.0795x; 1.0282x over previous
//
#include <hip/hip_runtime.h>
#include <math.h>

#define NQ 12
#define DIM 4096
#define KS 6
#define BB 256
#define SEQ 128
#define DEMB 512

// v8 = v7 (best: 42.1us / 129.7 harness) + DEFERRED EXPVALS:
//  - in-loop, each thread stores only its 3 Walsh partials (Q0,Q1,Q2) to
//    s_pq[k][3][512] (3 conflict-free b32 writes). The 39-bpermute/step/wave
//    shuffle machinery + 6-deep serial chains move to a one-shot epilogue
//    (wave k reduces step k; 6 waves run chain-parallel, no barriers).
//  - sign algebra derived from the verified chains by LINEARITY:
//    wire1=plain(sum Q1); wires2-5=plain(wave-signed sum Q2);
//    wires6-11=c-chain partial lane-parities on wall-signed sum Q2;
//    wire0=full-parity chain on wall-signed sum Q0.
//  - every B2's lgkmcnt(0) now drains 11 DS ops instead of 47+.
// All layouts / trips / pk-SU(2) gates / encoder / ring = v7-verbatim.
//
// Layouts (j = 12-bit state index, wire w <-> bit 11-w):
//   L_A: reg=bits0-2 (wires 11,10,9), lane=3-8, wave=9-11
//   L_B: reg=3-5 (8,7,6), lane=(0,1,2,6,7,8), wave=9-11
//   L_C: reg=6-8 (5,4,3), lane=0-5, wave=9-11
//   L_D: reg=9-11 (2,1,0), lane=0-5, wave=6-8
// Trips 1-2 intra-wave (buf0 + lgkmcnt fence); trip 3 cross-wave (B1);
// trip 4 = ring-folded scatter (buf1, B2).

typedef float f2 __attribute__((ext_vector_type(2)));

// packed complex 2x2 SU(2) gate: U = [[E0+iE1, E2+iE3],[-E2+iE3, E0-iE1]]
#define RG(P, W) { \
    f2 E01 = *(const f2*)&s_u[k][W][0]; \
    f2 E23 = *(const f2*)&s_u[k][W][2]; \
    f2 PR0 = (f2){ E01.x,  E01.x}; \
    f2 PI0 = (f2){-E01.y,  E01.y}; \
    f2 PR1 = (f2){ E23.x,  E23.x}; \
    f2 PI1 = (f2){-E23.y,  E23.y}; \
    _Pragma("unroll") \
    for (int r0 = 0; r0 < 8; ++r0) if (!(r0 & (1 << (P)))) { \
        int r1 = r0 | (1 << (P)); \
        f2 A = a[r0], Bv = a[r1]; \
        f2 As = (f2){A.y, A.x}, Bs = (f2){Bv.y, Bv.x}; \
        a[r0] = PR0*A  + PI0*As + PR1*Bv + PI1*Bs; \
        a[r1] = PR0*Bv - PI0*Bs - PR1*A  + PI1*As; \
    } }

#define BF_PLAIN(v, m) { float p_ = __shfl_xor(v, m, 64); v = v + p_; }
#define BF_SIGN(v, m)  { float p_ = __shfl_xor(v, m, 64); float d_ = v - p_; \
                         v = (lane & m) ? -d_ : d_; }

// wave-local LDS write->read ordering (no block barrier)
#define WAVE_FENCE() asm volatile("s_waitcnt lgkmcnt(0)" ::: "memory")

// block barrier without vmcnt drain (no VMEM ops in the K loop)
#define BARRIER() { asm volatile("s_waitcnt lgkmcnt(0)" ::: "memory"); \
                    __builtin_amdgcn_s_barrier(); }

__device__ __forceinline__ int swz14(int x) { return x ^ ((x >> 4) & 14); }

__global__ __launch_bounds__(512) void fused_kernel(
    const int* __restrict__ ids, const int* __restrict__ mask,
    const float* __restrict__ emb, const float* __restrict__ pw,
    const float* __restrict__ pb, const float* __restrict__ theta,
    const float* __restrict__ hw, const float* __restrict__ hb,
    float* __restrict__ readouts, float* __restrict__ logits,
    float* __restrict__ last)
{
    __shared__ __align__(16) f2    buf0[DIM];   // 32 KB (trips 1-3)
    __shared__ __align__(16) f2    buf1[DIM];   // 32 KB (trip 4 / enc)
    __shared__ __align__(16) float s_pq[KS][3][512];   // 36 KB Walsh partials
    __shared__ __align__(16) float s_u[KS][NQ][4];
    __shared__ float  s_rall[KS][NQ];
    __shared__ float  s_msum[4];
    __shared__ float  s_wred[2][NQ];
    __shared__ float  s_x[NQ];
    __shared__ float  s_hw[8 * NQ];
    __shared__ float  s_hb[8];

    int b = blockIdx.x;
    int tid = threadIdx.x;
    int lane = tid & 63, wave = tid >> 6;     // wave 0..7

    // ---------------- encoder (v1 verbatim) ----------------
    int*   s_ids = (int*)buf1;
    float* s_m   = (float*)buf1 + SEQ;
    float4* s_part = (float4*)buf0;           // [4][128]

    if (tid < SEQ) {
        s_ids[tid] = ids[b * SEQ + tid];
        s_m[tid]   = (float)mask[b * SEQ + tid];
    }
    if (tid >= 256 && tid < 256 + 8 * NQ) s_hw[tid - 256] = hw[tid - 256];
    if (tid >= 384 && tid < 392)          s_hb[tid - 384] = hb[tid - 384];
    __syncthreads();

    {
        int g = tid >> 7, e = tid & 127;
        float4 acc = make_float4(0.f, 0.f, 0.f, 0.f);
        float msum = 0.f;
        #pragma unroll 4
        for (int s = g; s < SEQ; s += 4) {
            float m = s_m[s];
            float4 v = ((const float4*)emb)[(size_t)s_ids[s] * 128 + e];
            acc.x = fmaf(m, v.x, acc.x);
            acc.y = fmaf(m, v.y, acc.y);
            acc.z = fmaf(m, v.z, acc.z);
            acc.w = fmaf(m, v.w, acc.w);
            msum += m;
        }
        __syncthreads();   // ids/m reads done before buf0 overlay write
        s_part[g * 128 + e] = acc;
        if (e == 0) s_msum[g] = msum;
    }
    __syncthreads();

    if (tid < 128) {
        float tm = fmaxf(s_msum[0] + s_msum[1] + s_msum[2] + s_msum[3], 1.f);
        float inv = 1.f / tm;
        float4 p0 = s_part[0 * 128 + tid], p1 = s_part[1 * 128 + tid];
        float4 p2 = s_part[2 * 128 + tid], p3 = s_part[3 * 128 + tid];
        float4 p;
        p.x = (p0.x + p1.x + p2.x + p3.x) * inv;
        p.y = (p0.y + p1.y + p2.y + p3.y) * inv;
        p.z = (p0.z + p1.z + p2.z + p3.z) * inv;
        p.w = (p0.w + p1.w + p2.w + p3.w) * inv;
        float z[NQ];
        #pragma unroll
        for (int i = 0; i < NQ; ++i) {
            float4 w4 = ((const float4*)pw)[i * 128 + tid];
            z[i] = p.x * w4.x + p.y * w4.y + p.z * w4.z + p.w * w4.w;
        }
        #pragma unroll
        for (int i = 0; i < NQ; ++i) {
            #pragma unroll
            for (int off = 32; off > 0; off >>= 1)
                z[i] += __shfl_xor(z[i], off, 64);
        }
        if ((tid & 63) == 0) {
            int w = tid >> 6;
            #pragma unroll
            for (int i = 0; i < NQ; ++i) s_wred[w][i] = z[i];
        }
    }
    __syncthreads();
    if (tid < NQ) {
        float d = pb[tid] + s_wred[0][tid] + s_wred[1][tid];
        s_x[tid] = tanhf(d) * 3.14159274101257324f;
    }
    __syncthreads();

    // ------ gate matrices: U = Rot(phi,te,om) @ RY(x), SU(2)-compressed ---
    // (harness-verified R2/R4) E0..E3; U = [[E0+iE1, E2+iE3],[-E2+iE3, E0-iE1]]
    if (tid < KS * NQ * 4) {
        int k = tid / 48;
        int rem = tid - k * 48;
        int w = rem >> 2, q = rem & 3;
        float ang = s_x[w];
        float cy = cosf(0.5f * ang), sy = sinf(0.5f * ang);
        const float* th = theta + (k * NQ + w) * 3;
        float phi = th[0], te = th[1], om = th[2];
        float ct = cosf(0.5f * te), st = sinf(0.5f * te);
        float a1 = -0.5f * (phi + om);
        float a2 =  0.5f * (phi - om);
        float ar =  cosf(a1) * ct, ai =  sinf(a1) * ct;   // R00
        float br = -cosf(a2) * st, bi = -sinf(a2) * st;   // R01
        float x1 = (q & 1) ? ai : ar;
        float x2 = (q & 1) ? bi : br;
        float E  = (q & 2) ? (x2 * cy - x1 * sy) : (x1 * cy + x2 * sy);
        s_u[k][w][q] = E;
    }

    // ---------------- constant addresses ----------------
    int T8 = tid << 3;
    int baseA  = swz14(T8);
    int baseA4 = baseA >> 1;          // float4 index; elem i at baseA4^i
    int addrB[8], addrC[8], addrD[8], idxP[8];
    #pragma unroll
    for (int r = 0; r < 8; ++r) {
        addrB[r] = swz14((lane & 7) + 8 * r + 64 * (lane >> 3) + 512 * wave);
        addrC[r] = swz14(lane + 64 * r + 512 * wave);
        int jD   = lane + 64 * wave + 512 * r;
        addrD[r] = swz14(jD);
        int b0 = (jD >> 11) & 1;
        int pref = b0, outv = 0;
        for (int w = 1; w < NQ; ++w) {
            pref ^= (jD >> (11 - w)) & 1;
            outv |= pref << (11 - w);
        }
        outv |= (b0 ^ pref) << 11;
        idxP[r] = swz14(outv);
    }

    f2 a[8];
    #pragma unroll
    for (int r = 0; r < 8; ++r) a[r] = (f2){0.f, 0.f};
    if (tid == 0) a[0].x = 1.f;
    __syncthreads();   // s_u ready, enc buf reads done

    // ---------------- K steps ----------------
    for (int k = 0; k < KS; ++k) {
        // phase 1 (L_A): wires 11,10,9
        RG(0, 11) RG(1, 10) RG(2, 9)

        // trip 1 (intra-wave): b128 dump -> gather L_B
        #pragma unroll
        for (int i = 0; i < 4; ++i)
            ((float4*)buf0)[baseA4 ^ i] =
                make_float4(a[2*i].x, a[2*i].y, a[2*i+1].x, a[2*i+1].y);
        WAVE_FENCE();
        #pragma unroll
        for (int r = 0; r < 8; ++r) a[r] = buf0[addrB[r]];

        // phase 2 (L_B): wires 8,7,6
        RG(0, 8) RG(1, 7) RG(2, 6)

        // trip 2 (intra-wave): dump L_B -> gather L_C
        #pragma unroll
        for (int r = 0; r < 8; ++r) buf0[addrB[r]] = a[r];
        WAVE_FENCE();
        #pragma unroll
        for (int r = 0; r < 8; ++r) a[r] = buf0[addrC[r]];

        // phase 3 (L_C): wires 5,4,3
        RG(0, 5) RG(1, 4) RG(2, 3)

        // trip 3 (cross-wave): dump L_C -> barrier -> gather L_D
        #pragma unroll
        for (int r = 0; r < 8; ++r) buf0[addrC[r]] = a[r];
        BARRIER();                                         // B1 (lgkm-only)
        #pragma unroll
        for (int r = 0; r < 8; ++r) a[r] = buf0[addrD[r]];

        // phase 4 (L_D): wires 2,1,0
        RG(0, 2) RG(1, 1) RG(2, 0)

        // trip 4: issue ring scatter FIRST
        #pragma unroll
        for (int r = 0; r < 8; ++r) buf1[idxP[r]] = a[r];

        // Walsh partials only -> LDS (expvals deferred to epilogue)
        {
            float p[8];
            #pragma unroll
            for (int r = 0; r < 8; ++r)
                p[r] = a[r].x * a[r].x + a[r].y * a[r].y;
            float Q1 = (p[0]+p[1]+p[6]+p[7]) - (p[2]+p[3]+p[4]+p[5]);
            float Q2 = (p[0]+p[3]+p[5]+p[6]) - (p[1]+p[2]+p[4]+p[7]);
            float Q0 = (p[0]+p[3]+p[4]+p[7]) - (p[1]+p[2]+p[5]+p[6]);
            s_pq[k][0][tid] = Q0;
            s_pq[k][1][tid] = Q1;
            s_pq[k][2][tid] = Q2;
        }

        BARRIER();                                         // B2 (lgkm-only)
        #pragma unroll
        for (int i = 0; i < 4; ++i) {
            float4 v = ((float4*)buf1)[baseA4 ^ i];
            a[2*i]   = (f2){v.x, v.y};
            a[2*i+1] = (f2){v.z, v.w};
        }
    }

    // ---------------- epilogue: one-shot Walsh reductions ----------------
    BARRIER();   // s_pq complete
    if (wave < KS) {
        int k = wave;
        // fold original-wave (j[8:6]) signs at load time (linearity)
        float sA = 0.f, sB0 = 0.f, sB1 = 0.f, sB2 = 0.f, sB3 = 0.f, sC = 0.f;
        #pragma unroll
        for (int w2 = 0; w2 < 8; ++w2) {
            float Q0v = s_pq[k][0][(w2 << 6) | lane];
            float Q1v = s_pq[k][1][(w2 << 6) | lane];
            float Q2v = s_pq[k][2][(w2 << 6) | lane];
            int w2b_  = (w2 >> 2) & 1;
            int w12_  = ((w2 >> 1) ^ (w2 >> 2)) & 1;
            int wall_ = (w2 ^ (w2 >> 1) ^ (w2 >> 2)) & 1;
            sA  += Q1v;
            sB0 += Q2v;
            sB1 += w2b_  ? -Q2v : Q2v;
            sB2 += w12_  ? -Q2v : Q2v;
            sB3 += wall_ ? -Q2v : Q2v;
            sC  += wall_ ? -Q0v : Q0v;
        }
        // plain allreduces: wires 1..5
        float v5s = sB3;
        BF_PLAIN(sA,32)  BF_PLAIN(sA,16)  BF_PLAIN(sA,8)
        BF_PLAIN(sA,4)   BF_PLAIN(sA,2)   BF_PLAIN(sA,1)
        BF_PLAIN(sB0,32) BF_PLAIN(sB0,16) BF_PLAIN(sB0,8)
        BF_PLAIN(sB0,4)  BF_PLAIN(sB0,2)  BF_PLAIN(sB0,1)
        BF_PLAIN(sB1,32) BF_PLAIN(sB1,16) BF_PLAIN(sB1,8)
        BF_PLAIN(sB1,4)  BF_PLAIN(sB1,2)  BF_PLAIN(sB1,1)
        BF_PLAIN(sB2,32) BF_PLAIN(sB2,16) BF_PLAIN(sB2,8)
        BF_PLAIN(sB2,4)  BF_PLAIN(sB2,2)  BF_PLAIN(sB2,1)
        BF_PLAIN(v5s,32) BF_PLAIN(v5s,16) BF_PLAIN(v5s,8)
        BF_PLAIN(v5s,4)  BF_PLAIN(v5s,2)  BF_PLAIN(v5s,1)
        // wire 0: full lane-parity chain on sC
        BF_SIGN(sC,32) BF_SIGN(sC,16) BF_SIGN(sC,8)
        BF_SIGN(sC,4)  BF_SIGN(sC,2)  BF_SIGN(sC,1)
        // wires 6..11: c-chain partial parities on sB3
        float c = sB3;
        BF_SIGN(c,32);
        float w6v = c; BF_PLAIN(w6v,16) BF_PLAIN(w6v,8) BF_PLAIN(w6v,4)
                       BF_PLAIN(w6v,2)  BF_PLAIN(w6v,1)
        BF_SIGN(c,16);
        float w7v = c; BF_PLAIN(w7v,8) BF_PLAIN(w7v,4)
                       BF_PLAIN(w7v,2) BF_PLAIN(w7v,1)
        BF_SIGN(c,8);
        float w8v = c; BF_PLAIN(w8v,4) BF_PLAIN(w8v,2) BF_PLAIN(w8v,1)
        BF_SIGN(c,4);
        float w9v = c; BF_PLAIN(w9v,2) BF_PLAIN(w9v,1)
        BF_SIGN(c,2);
        float w10v = c; BF_PLAIN(w10v,1)
        BF_SIGN(c,1);
        if (lane == 0) {
            s_rall[k][0]  = sC;
            s_rall[k][1]  = sA;
            s_rall[k][2]  = sB0;
            s_rall[k][3]  = sB1;
            s_rall[k][4]  = sB2;
            s_rall[k][5]  = v5s;
            s_rall[k][6]  = w6v;
            s_rall[k][7]  = w7v;
            s_rall[k][8]  = w8v;
            s_rall[k][9]  = w9v;
            s_rall[k][10] = w10v;
            s_rall[k][11] = c;
        }
    }

    // ---------------- final stores (v7 verbatim) ----------------
    BARRIER();   // s_rall complete, visible to all waves
    if (tid < KS * NQ) {                       // 72 threads: readouts
        int k = tid / NQ, i = tid - k * NQ;
        readouts[(k * BB + b) * NQ + i] = s_rall[k][i];
    }
    if (tid >= 128 && tid < 128 + KS * 8) {    // wave 2: logits + last
        int t = tid - 128;
        int k = t >> 3, c = t & 7;
        float acc2 = s_hb[c];
        #pragma unroll
        for (int i = 0; i < NQ; ++i)
            acc2 = fmaf(s_rall[k][i], s_hw[c * NQ + i], acc2);
        logits[(k * BB + b) * 8 + c] = acc2;
        if (k == KS - 1) last[b * 8 + c] = acc2;
    }
}

extern "C" void kernel_launch(void* const* d_in, const int* in_sizes, int n_in,
                              void* d_out, int out_size, void* d_ws, size_t ws_size,
                              hipStream_t stream) {
    const int*   ids   = (const int*)d_in[0];
    const int*   mask  = (const int*)d_in[1];
    const float* emb   = (const float*)d_in[2];
    const float* pw    = (const float*)d_in[3];
    const float* pb    = (const float*)d_in[4];
    const float* theta = (const float*)d_in[5];
    const float* hw    = (const float*)d_in[6];
    const float* hb    = (const float*)d_in[7];
    float* out = (float*)d_out;

    float* readouts = out + KS * BB * 8;              // [K,B,NQ]
    float* last     = out + KS * BB * 8 + KS * BB * NQ;

    fused_kernel<<<BB, 512, 0, stream>>>(ids, mask, emb, pw, pb, theta,
                                         hw, hb, readouts, out, last);
}

// Round 9
// 125.229 us; speedup vs baseline: 1.0871x; 1.0070x over previous
//
#include <hip/hip_runtime.h>
#include <math.h>

#define NQ 12
#define DIM 4096
#define KS 6
#define BB 256
#define SEQ 128
#define DEMB 512

// v9 (resubmit -- R8 was an infra failure, no kernel verdict):
// v8 (126.1 harness) + DS-instruction-count cuts (83 -> 65 per step):
//  - trip2 dump contiguous: 4x ds_write_b128 via the v1-verified baseA4^i
//    identity (was 8x b64 scattered). Trip images are trip-local, so only
//    trip2's gather changes: addrC2 derived from the L_B owner map
//    (owner lane = {j[8:6],j[2:0]}, reg = j[5:3]); same 4-way conflict class.
//    WAR-safe: phase-2 gates' data deps order the dump after trip-1 reads.
//  - gate coefficients preloaded once per step: float4 cf[12] (12x b128
//    broadcast) instead of 24 interleaved f2 loads with per-RG lgkm stalls.
//  - Walsh partials: one ds_write_b128 into s_pq[k][tid][4] (was 3x b32).
// All gate math / layouts / trip3-4 / expval algebra / encoder = v8-verbatim.
//
// Layouts (j = 12-bit state index, wire w <-> bit 11-w):
//   L_A: reg=bits0-2 (wires 11,10,9), lane=3-8, wave=9-11
//   L_B: reg=3-5 (8,7,6), lane=(0,1,2,6,7,8), wave=9-11
//   L_C: reg=6-8 (5,4,3), lane=0-5, wave=9-11
//   L_D: reg=9-11 (2,1,0), lane=0-5, wave=6-8
// Trips 1-2 intra-wave (buf0 + lgkmcnt fence); trip 3 cross-wave (B1);
// trip 4 = ring-folded scatter (buf1, B2). Expvals deferred (epilogue).

typedef float f2 __attribute__((ext_vector_type(2)));

// packed complex 2x2 SU(2) gate: U = [[E0+iE1, E2+iE3],[-E2+iE3, E0-iE1]]
// coefficients from per-step preloaded cf[W] (static index)
#define RG(P, W) { \
    float4 E = cf[W]; \
    f2 PR0 = (f2){ E.x,  E.x}; \
    f2 PI0 = (f2){-E.y,  E.y}; \
    f2 PR1 = (f2){ E.z,  E.z}; \
    f2 PI1 = (f2){-E.w,  E.w}; \
    _Pragma("unroll") \
    for (int r0 = 0; r0 < 8; ++r0) if (!(r0 & (1 << (P)))) { \
        int r1 = r0 | (1 << (P)); \
        f2 A = a[r0], Bv = a[r1]; \
        f2 As = (f2){A.y, A.x}, Bs = (f2){Bv.y, Bv.x}; \
        a[r0] = PR0*A  + PI0*As + PR1*Bv + PI1*Bs; \
        a[r1] = PR0*Bv - PI0*Bs - PR1*A  + PI1*As; \
    } }

#define BF_PLAIN(v, m) { float p_ = __shfl_xor(v, m, 64); v = v + p_; }
#define BF_SIGN(v, m)  { float p_ = __shfl_xor(v, m, 64); float d_ = v - p_; \
                         v = (lane & m) ? -d_ : d_; }

// wave-local LDS write->read ordering (no block barrier)
#define WAVE_FENCE() asm volatile("s_waitcnt lgkmcnt(0)" ::: "memory")

// block barrier without vmcnt drain (no VMEM ops in the K loop)
#define BARRIER() { asm volatile("s_waitcnt lgkmcnt(0)" ::: "memory"); \
                    __builtin_amdgcn_s_barrier(); }

__device__ __forceinline__ int swz14(int x) { return x ^ ((x >> 4) & 14); }

__global__ __launch_bounds__(512) void fused_kernel(
    const int* __restrict__ ids, const int* __restrict__ mask,
    const float* __restrict__ emb, const float* __restrict__ pw,
    const float* __restrict__ pb, const float* __restrict__ theta,
    const float* __restrict__ hw, const float* __restrict__ hb,
    float* __restrict__ readouts, float* __restrict__ logits,
    float* __restrict__ last)
{
    __shared__ __align__(16) f2    buf0[DIM];   // 32 KB (trips 1-3)
    __shared__ __align__(16) f2    buf1[DIM];   // 32 KB (trip 4 / enc)
    __shared__ __align__(16) float s_pq[KS][512][4];   // 48 KB Walsh partials
    __shared__ __align__(16) float s_u[KS][NQ][4];
    __shared__ float  s_rall[KS][NQ];
    __shared__ float  s_msum[4];
    __shared__ float  s_wred[2][NQ];
    __shared__ float  s_x[NQ];
    __shared__ float  s_hw[8 * NQ];
    __shared__ float  s_hb[8];

    int b = blockIdx.x;
    int tid = threadIdx.x;
    int lane = tid & 63, wave = tid >> 6;     // wave 0..7

    // ---------------- encoder (v1 verbatim) ----------------
    int*   s_ids = (int*)buf1;
    float* s_m   = (float*)buf1 + SEQ;
    float4* s_part = (float4*)buf0;           // [4][128]

    if (tid < SEQ) {
        s_ids[tid] = ids[b * SEQ + tid];
        s_m[tid]   = (float)mask[b * SEQ + tid];
    }
    if (tid >= 256 && tid < 256 + 8 * NQ) s_hw[tid - 256] = hw[tid - 256];
    if (tid >= 384 && tid < 392)          s_hb[tid - 384] = hb[tid - 384];
    __syncthreads();

    {
        int g = tid >> 7, e = tid & 127;
        float4 acc = make_float4(0.f, 0.f, 0.f, 0.f);
        float msum = 0.f;
        #pragma unroll 4
        for (int s = g; s < SEQ; s += 4) {
            float m = s_m[s];
            float4 v = ((const float4*)emb)[(size_t)s_ids[s] * 128 + e];
            acc.x = fmaf(m, v.x, acc.x);
            acc.y = fmaf(m, v.y, acc.y);
            acc.z = fmaf(m, v.z, acc.z);
            acc.w = fmaf(m, v.w, acc.w);
            msum += m;
        }
        __syncthreads();   // ids/m reads done before buf0 overlay write
        s_part[g * 128 + e] = acc;
        if (e == 0) s_msum[g] = msum;
    }
    __syncthreads();

    if (tid < 128) {
        float tm = fmaxf(s_msum[0] + s_msum[1] + s_msum[2] + s_msum[3], 1.f);
        float inv = 1.f / tm;
        float4 p0 = s_part[0 * 128 + tid], p1 = s_part[1 * 128 + tid];
        float4 p2 = s_part[2 * 128 + tid], p3 = s_part[3 * 128 + tid];
        float4 p;
        p.x = (p0.x + p1.x + p2.x + p3.x) * inv;
        p.y = (p0.y + p1.y + p2.y + p3.y) * inv;
        p.z = (p0.z + p1.z + p2.z + p3.z) * inv;
        p.w = (p0.w + p1.w + p2.w + p3.w) * inv;
        float z[NQ];
        #pragma unroll
        for (int i = 0; i < NQ; ++i) {
            float4 w4 = ((const float4*)pw)[i * 128 + tid];
            z[i] = p.x * w4.x + p.y * w4.y + p.z * w4.z + p.w * w4.w;
        }
        #pragma unroll
        for (int i = 0; i < NQ; ++i) {
            #pragma unroll
            for (int off = 32; off > 0; off >>= 1)
                z[i] += __shfl_xor(z[i], off, 64);
        }
        if ((tid & 63) == 0) {
            int w = tid >> 6;
            #pragma unroll
            for (int i = 0; i < NQ; ++i) s_wred[w][i] = z[i];
        }
    }
    __syncthreads();
    if (tid < NQ) {
        float d = pb[tid] + s_wred[0][tid] + s_wred[1][tid];
        s_x[tid] = tanhf(d) * 3.14159274101257324f;
    }
    __syncthreads();

    // ------ gate matrices: U = Rot(phi,te,om) @ RY(x), SU(2)-compressed ---
    // (harness-verified R2/R4) E0..E3; U = [[E0+iE1, E2+iE3],[-E2+iE3, E0-iE1]]
    if (tid < KS * NQ * 4) {
        int k = tid / 48;
        int rem = tid - k * 48;
        int w = rem >> 2, q = rem & 3;
        float ang = s_x[w];
        float cy = cosf(0.5f * ang), sy = sinf(0.5f * ang);
        const float* th = theta + (k * NQ + w) * 3;
        float phi = th[0], te = th[1], om = th[2];
        float ct = cosf(0.5f * te), st = sinf(0.5f * te);
        float a1 = -0.5f * (phi + om);
        float a2 =  0.5f * (phi - om);
        float ar =  cosf(a1) * ct, ai =  sinf(a1) * ct;   // R00
        float br = -cosf(a2) * st, bi = -sinf(a2) * st;   // R01
        float x1 = (q & 1) ? ai : ar;
        float x2 = (q & 1) ? bi : br;
        float E  = (q & 2) ? (x2 * cy - x1 * sy) : (x1 * cy + x2 * sy);
        s_u[k][w][q] = E;
    }

    // ---------------- constant addresses ----------------
    int T8 = tid << 3;
    int baseA  = swz14(T8);
    int baseA4 = baseA >> 1;          // float4 index; elem i at baseA4^i
    int addrB[8], addrC2[8], addrC[8], addrD[8], idxP[8];
    #pragma unroll
    for (int r = 0; r < 8; ++r) {
        addrB[r]  = swz14((lane & 7) + 8 * r + 64 * (lane >> 3) + 512 * wave);
        // trip2 gather from trip2's contiguous (owner-major) image:
        // amp j at 512*j[11:9] + 64*j[8:6] + 8*j[2:0] + j[5:3]
        addrC2[r] = swz14(512 * wave + 64 * r + 8 * (lane & 7) + (lane >> 3));
        addrC[r]  = swz14(lane + 64 * r + 512 * wave);   // trip3 dump (p=j)
        int jD    = lane + 64 * wave + 512 * r;
        addrD[r]  = swz14(jD);
        int b0 = (jD >> 11) & 1;
        int pref = b0, outv = 0;
        for (int w = 1; w < NQ; ++w) {
            pref ^= (jD >> (11 - w)) & 1;
            outv |= pref << (11 - w);
        }
        outv |= (b0 ^ pref) << 11;
        idxP[r] = swz14(outv);
    }

    f2 a[8];
    #pragma unroll
    for (int r = 0; r < 8; ++r) a[r] = (f2){0.f, 0.f};
    if (tid == 0) a[0].x = 1.f;
    __syncthreads();   // s_u ready, enc buf reads done

    // ---------------- K steps ----------------
    for (int k = 0; k < KS; ++k) {
        // preload this step's 12 gate coefficient quads (b128 broadcasts)
        float4 cf[NQ];
        #pragma unroll
        for (int w = 0; w < NQ; ++w) cf[w] = *(const float4*)&s_u[k][w][0];

        // phase 1 (L_A): wires 11,10,9
        RG(0, 11) RG(1, 10) RG(2, 9)

        // trip 1 (intra-wave): b128 dump -> gather L_B
        #pragma unroll
        for (int i = 0; i < 4; ++i)
            ((float4*)buf0)[baseA4 ^ i] =
                make_float4(a[2*i].x, a[2*i].y, a[2*i+1].x, a[2*i+1].y);
        WAVE_FENCE();
        #pragma unroll
        for (int r = 0; r < 8; ++r) a[r] = buf0[addrB[r]];

        // phase 2 (L_B): wires 8,7,6
        RG(0, 8) RG(1, 7) RG(2, 6)

        // trip 2 (intra-wave): CONTIGUOUS b128 dump -> gather L_C (addrC2)
        // (safe: phase-2 gates' data deps order this after trip-1 reads)
        #pragma unroll
        for (int i = 0; i < 4; ++i)
            ((float4*)buf0)[baseA4 ^ i] =
                make_float4(a[2*i].x, a[2*i].y, a[2*i+1].x, a[2*i+1].y);
        WAVE_FENCE();
        #pragma unroll
        for (int r = 0; r < 8; ++r) a[r] = buf0[addrC2[r]];

        // phase 3 (L_C): wires 5,4,3
        RG(0, 5) RG(1, 4) RG(2, 3)

        // trip 3 (cross-wave): dump L_C (p=j image) -> barrier -> gather L_D
        #pragma unroll
        for (int r = 0; r < 8; ++r) buf0[addrC[r]] = a[r];
        BARRIER();                                         // B1 (lgkm-only)
        #pragma unroll
        for (int r = 0; r < 8; ++r) a[r] = buf0[addrD[r]];

        // phase 4 (L_D): wires 2,1,0
        RG(0, 2) RG(1, 1) RG(2, 0)

        // trip 4: issue ring scatter FIRST
        #pragma unroll
        for (int r = 0; r < 8; ++r) buf1[idxP[r]] = a[r];

        // Walsh partials -> single b128 (expvals deferred to epilogue)
        {
            float p[8];
            #pragma unroll
            for (int r = 0; r < 8; ++r)
                p[r] = a[r].x * a[r].x + a[r].y * a[r].y;
            float Q1 = (p[0]+p[1]+p[6]+p[7]) - (p[2]+p[3]+p[4]+p[5]);
            float Q2 = (p[0]+p[3]+p[5]+p[6]) - (p[1]+p[2]+p[4]+p[7]);
            float Q0 = (p[0]+p[3]+p[4]+p[7]) - (p[1]+p[2]+p[5]+p[6]);
            *(float4*)&s_pq[k][tid][0] = make_float4(Q0, Q1, Q2, 0.f);
        }

        BARRIER();                                         // B2 (lgkm-only)
        #pragma unroll
        for (int i = 0; i < 4; ++i) {
            float4 v = ((float4*)buf1)[baseA4 ^ i];
            a[2*i]   = (f2){v.x, v.y};
            a[2*i+1] = (f2){v.z, v.w};
        }
    }

    // ---------------- epilogue: one-shot Walsh reductions ----------------
    BARRIER();   // s_pq complete
    if (wave < KS) {
        int k = wave;
        // fold original-wave (j[8:6]) signs at load time (linearity)
        float sA = 0.f, sB0 = 0.f, sB1 = 0.f, sB2 = 0.f, sB3 = 0.f, sC = 0.f;
        #pragma unroll
        for (int w2 = 0; w2 < 8; ++w2) {
            float4 Qv = *(const float4*)&s_pq[k][(w2 << 6) | lane][0];
            float Q0v = Qv.x, Q1v = Qv.y, Q2v = Qv.z;
            int w2b_  = (w2 >> 2) & 1;
            int w12_  = ((w2 >> 1) ^ (w2 >> 2)) & 1;
            int wall_ = (w2 ^ (w2 >> 1) ^ (w2 >> 2)) & 1;
            sA  += Q1v;
            sB0 += Q2v;
            sB1 += w2b_  ? -Q2v : Q2v;
            sB2 += w12_  ? -Q2v : Q2v;
            sB3 += wall_ ? -Q2v : Q2v;
            sC  += wall_ ? -Q0v : Q0v;
        }
        // plain allreduces: wires 1..5
        float v5s = sB3;
        BF_PLAIN(sA,32)  BF_PLAIN(sA,16)  BF_PLAIN(sA,8)
        BF_PLAIN(sA,4)   BF_PLAIN(sA,2)   BF_PLAIN(sA,1)
        BF_PLAIN(sB0,32) BF_PLAIN(sB0,16) BF_PLAIN(sB0,8)
        BF_PLAIN(sB0,4)  BF_PLAIN(sB0,2)  BF_PLAIN(sB0,1)
        BF_PLAIN(sB1,32) BF_PLAIN(sB1,16) BF_PLAIN(sB1,8)
        BF_PLAIN(sB1,4)  BF_PLAIN(sB1,2)  BF_PLAIN(sB1,1)
        BF_PLAIN(sB2,32) BF_PLAIN(sB2,16) BF_PLAIN(sB2,8)
        BF_PLAIN(sB2,4)  BF_PLAIN(sB2,2)  BF_PLAIN(sB2,1)
        BF_PLAIN(v5s,32) BF_PLAIN(v5s,16) BF_PLAIN(v5s,8)
        BF_PLAIN(v5s,4)  BF_PLAIN(v5s,2)  BF_PLAIN(v5s,1)
        // wire 0: full lane-parity chain on sC
        BF_SIGN(sC,32) BF_SIGN(sC,16) BF_SIGN(sC,8)
        BF_SIGN(sC,4)  BF_SIGN(sC,2)  BF_SIGN(sC,1)
        // wires 6..11: c-chain partial parities on sB3
        float c = sB3;
        BF_SIGN(c,32);
        float w6v = c; BF_PLAIN(w6v,16) BF_PLAIN(w6v,8) BF_PLAIN(w6v,4)
                       BF_PLAIN(w6v,2)  BF_PLAIN(w6v,1)
        BF_SIGN(c,16);
        float w7v = c; BF_PLAIN(w7v,8) BF_PLAIN(w7v,4)
                       BF_PLAIN(w7v,2) BF_PLAIN(w7v,1)
        BF_SIGN(c,8);
        float w8v = c; BF_PLAIN(w8v,4) BF_PLAIN(w8v,2) BF_PLAIN(w8v,1)
        BF_SIGN(c,4);
        float w9v = c; BF_PLAIN(w9v,2) BF_PLAIN(w9v,1)
        BF_SIGN(c,2);
        float w10v = c; BF_PLAIN(w10v,1)
        BF_SIGN(c,1);
        if (lane == 0) {
            s_rall[k][0]  = sC;
            s_rall[k][1]  = sA;
            s_rall[k][2]  = sB0;
            s_rall[k][3]  = sB1;
            s_rall[k][4]  = sB2;
            s_rall[k][5]  = v5s;
            s_rall[k][6]  = w6v;
            s_rall[k][7]  = w7v;
            s_rall[k][8]  = w8v;
            s_rall[k][9]  = w9v;
            s_rall[k][10] = w10v;
            s_rall[k][11] = c;
        }
    }

    // ---------------- final stores (v7 verbatim) ----------------
    BARRIER();   // s_rall complete, visible to all waves
    if (tid < KS * NQ) {                       // 72 threads: readouts
        int k = tid / NQ, i = tid - k * NQ;
        readouts[(k * BB + b) * NQ + i] = s_rall[k][i];
    }
    if (tid >= 128 && tid < 128 + KS * 8) {    // wave 2: logits + last
        int t = tid - 128;
        int k = t >> 3, c = t & 7;
        float acc2 = s_hb[c];
        #pragma unroll
        for (int i = 0; i < NQ; ++i)
            acc2 = fmaf(s_rall[k][i], s_hw[c * NQ + i], acc2);
        logits[(k * BB + b) * 8 + c] = acc2;
        if (k == KS - 1) last[b * 8 + c] = acc2;
    }
}

extern "C" void kernel_launch(void* const* d_in, const int* in_sizes, int n_in,
                              void* d_out, int out_size, void* d_ws, size_t ws_size,
                              hipStream_t stream) {
    const int*   ids   = (const int*)d_in[0];
    const int*   mask  = (const int*)d_in[1];
    const float* emb   = (const float*)d_in[2];
    const float* pw    = (const float*)d_in[3];
    const float* pb    = (const float*)d_in[4];
    const float* theta = (const float*)d_in[5];
    const float* hw    = (const float*)d_in[6];
    const float* hb    = (const float*)d_in[7];
    float* out = (float*)d_out;

    float* readouts = out + KS * BB * 8;              // [K,B,NQ]
    float* last     = out + KS * BB * 8 + KS * BB * NQ;

    fused_kernel<<<BB, 512, 0, stream>>>(ids, mask, emb, pw, pb, theta,
                                         hw, hb, readouts, out, last);
}

// Round 10
// 125.145 us; speedup vs baseline: 1.0879x; 1.0007x over previous
//
#include <hip/hip_runtime.h>
#include <math.h>

#define NQ 12
#define DIM 4096
#define KS 6
#define BB 256
#define SEQ 128
#define DEMB 512

// v10 = v9 (125.2 harness) + two stall/dead-work cuts:
//  - intra-wave trip fences: s_waitcnt lgkmcnt(0) -> compiler-only fence
//    (asm ""::: "memory"). Per-wave DS ops execute in order, so the gather
//    reads (program-order after the dump writes) return written data; the
//    compiler's auto fine-grained lgkmcnt(N) before first VALU use covers
//    the register hazard. Removes 12 full LDS round-trip issue stalls.
//    B1/B2 keep lgkmcnt(0) (cross-wave visibility needs completion).
//  - last step (k=KS-1): skip ring scatter + B2 + buf1 gather (expvals are
//    pre-ring; this work only feeds a nonexistent next step). -12 DS ops,
//    -1 barrier; epilogue BARRIER fences s_pq[5].
// All gate math / layouts / trips / expval algebra / encoder = v9-verbatim.
//
// Layouts (j = 12-bit state index, wire w <-> bit 11-w):
//   L_A: reg=bits0-2 (wires 11,10,9), lane=3-8, wave=9-11
//   L_B: reg=3-5 (8,7,6), lane=(0,1,2,6,7,8), wave=9-11
//   L_C: reg=6-8 (5,4,3), lane=0-5, wave=9-11
//   L_D: reg=9-11 (2,1,0), lane=0-5, wave=6-8
// Trips 1-2 intra-wave (buf0); trip 3 cross-wave (B1); trip 4 = ring-folded
// scatter (buf1, B2). Expvals deferred (epilogue Walsh).

typedef float f2 __attribute__((ext_vector_type(2)));

// packed complex 2x2 SU(2) gate: U = [[E0+iE1, E2+iE3],[-E2+iE3, E0-iE1]]
// coefficients from per-step preloaded cf[W] (static index)
#define RG(P, W) { \
    float4 E = cf[W]; \
    f2 PR0 = (f2){ E.x,  E.x}; \
    f2 PI0 = (f2){-E.y,  E.y}; \
    f2 PR1 = (f2){ E.z,  E.z}; \
    f2 PI1 = (f2){-E.w,  E.w}; \
    _Pragma("unroll") \
    for (int r0 = 0; r0 < 8; ++r0) if (!(r0 & (1 << (P)))) { \
        int r1 = r0 | (1 << (P)); \
        f2 A = a[r0], Bv = a[r1]; \
        f2 As = (f2){A.y, A.x}, Bs = (f2){Bv.y, Bv.x}; \
        a[r0] = PR0*A  + PI0*As + PR1*Bv + PI1*Bs; \
        a[r1] = PR0*Bv - PI0*Bs - PR1*A  + PI1*As; \
    } }

#define BF_PLAIN(v, m) { float p_ = __shfl_xor(v, m, 64); v = v + p_; }
#define BF_SIGN(v, m)  { float p_ = __shfl_xor(v, m, 64); float d_ = v - p_; \
                         v = (lane & m) ? -d_ : d_; }

// compiler-only ordering fence: per-wave DS ops execute in order in HW;
// auto-waitcnt before first use covers the register hazard.
#define WAVE_FENCE() asm volatile("" ::: "memory")

// block barrier without vmcnt drain (no VMEM ops in the K loop);
// lgkmcnt(0) required: writes must COMPLETE before s_barrier for
// cross-wave visibility.
#define BARRIER() { asm volatile("s_waitcnt lgkmcnt(0)" ::: "memory"); \
                    __builtin_amdgcn_s_barrier(); }

__device__ __forceinline__ int swz14(int x) { return x ^ ((x >> 4) & 14); }

__global__ __launch_bounds__(512) void fused_kernel(
    const int* __restrict__ ids, const int* __restrict__ mask,
    const float* __restrict__ emb, const float* __restrict__ pw,
    const float* __restrict__ pb, const float* __restrict__ theta,
    const float* __restrict__ hw, const float* __restrict__ hb,
    float* __restrict__ readouts, float* __restrict__ logits,
    float* __restrict__ last)
{
    __shared__ __align__(16) f2    buf0[DIM];   // 32 KB (trips 1-3)
    __shared__ __align__(16) f2    buf1[DIM];   // 32 KB (trip 4 / enc)
    __shared__ __align__(16) float s_pq[KS][512][4];   // 48 KB Walsh partials
    __shared__ __align__(16) float s_u[KS][NQ][4];
    __shared__ float  s_rall[KS][NQ];
    __shared__ float  s_msum[4];
    __shared__ float  s_wred[2][NQ];
    __shared__ float  s_x[NQ];
    __shared__ float  s_hw[8 * NQ];
    __shared__ float  s_hb[8];

    int b = blockIdx.x;
    int tid = threadIdx.x;
    int lane = tid & 63, wave = tid >> 6;     // wave 0..7

    // ---------------- encoder (v1 verbatim) ----------------
    int*   s_ids = (int*)buf1;
    float* s_m   = (float*)buf1 + SEQ;
    float4* s_part = (float4*)buf0;           // [4][128]

    if (tid < SEQ) {
        s_ids[tid] = ids[b * SEQ + tid];
        s_m[tid]   = (float)mask[b * SEQ + tid];
    }
    if (tid >= 256 && tid < 256 + 8 * NQ) s_hw[tid - 256] = hw[tid - 256];
    if (tid >= 384 && tid < 392)          s_hb[tid - 384] = hb[tid - 384];
    __syncthreads();

    {
        int g = tid >> 7, e = tid & 127;
        float4 acc = make_float4(0.f, 0.f, 0.f, 0.f);
        float msum = 0.f;
        #pragma unroll 4
        for (int s = g; s < SEQ; s += 4) {
            float m = s_m[s];
            float4 v = ((const float4*)emb)[(size_t)s_ids[s] * 128 + e];
            acc.x = fmaf(m, v.x, acc.x);
            acc.y = fmaf(m, v.y, acc.y);
            acc.z = fmaf(m, v.z, acc.z);
            acc.w = fmaf(m, v.w, acc.w);
            msum += m;
        }
        __syncthreads();   // ids/m reads done before buf0 overlay write
        s_part[g * 128 + e] = acc;
        if (e == 0) s_msum[g] = msum;
    }
    __syncthreads();

    if (tid < 128) {
        float tm = fmaxf(s_msum[0] + s_msum[1] + s_msum[2] + s_msum[3], 1.f);
        float inv = 1.f / tm;
        float4 p0 = s_part[0 * 128 + tid], p1 = s_part[1 * 128 + tid];
        float4 p2 = s_part[2 * 128 + tid], p3 = s_part[3 * 128 + tid];
        float4 p;
        p.x = (p0.x + p1.x + p2.x + p3.x) * inv;
        p.y = (p0.y + p1.y + p2.y + p3.y) * inv;
        p.z = (p0.z + p1.z + p2.z + p3.z) * inv;
        p.w = (p0.w + p1.w + p2.w + p3.w) * inv;
        float z[NQ];
        #pragma unroll
        for (int i = 0; i < NQ; ++i) {
            float4 w4 = ((const float4*)pw)[i * 128 + tid];
            z[i] = p.x * w4.x + p.y * w4.y + p.z * w4.z + p.w * w4.w;
        }
        #pragma unroll
        for (int i = 0; i < NQ; ++i) {
            #pragma unroll
            for (int off = 32; off > 0; off >>= 1)
                z[i] += __shfl_xor(z[i], off, 64);
        }
        if ((tid & 63) == 0) {
            int w = tid >> 6;
            #pragma unroll
            for (int i = 0; i < NQ; ++i) s_wred[w][i] = z[i];
        }
    }
    __syncthreads();
    if (tid < NQ) {
        float d = pb[tid] + s_wred[0][tid] + s_wred[1][tid];
        s_x[tid] = tanhf(d) * 3.14159274101257324f;
    }
    __syncthreads();

    // ------ gate matrices: U = Rot(phi,te,om) @ RY(x), SU(2)-compressed ---
    // (harness-verified R2/R4) E0..E3; U = [[E0+iE1, E2+iE3],[-E2+iE3, E0-iE1]]
    if (tid < KS * NQ * 4) {
        int k = tid / 48;
        int rem = tid - k * 48;
        int w = rem >> 2, q = rem & 3;
        float ang = s_x[w];
        float cy = cosf(0.5f * ang), sy = sinf(0.5f * ang);
        const float* th = theta + (k * NQ + w) * 3;
        float phi = th[0], te = th[1], om = th[2];
        float ct = cosf(0.5f * te), st = sinf(0.5f * te);
        float a1 = -0.5f * (phi + om);
        float a2 =  0.5f * (phi - om);
        float ar =  cosf(a1) * ct, ai =  sinf(a1) * ct;   // R00
        float br = -cosf(a2) * st, bi = -sinf(a2) * st;   // R01
        float x1 = (q & 1) ? ai : ar;
        float x2 = (q & 1) ? bi : br;
        float E  = (q & 2) ? (x2 * cy - x1 * sy) : (x1 * cy + x2 * sy);
        s_u[k][w][q] = E;
    }

    // ---------------- constant addresses ----------------
    int T8 = tid << 3;
    int baseA  = swz14(T8);
    int baseA4 = baseA >> 1;          // float4 index; elem i at baseA4^i
    int addrB[8], addrC2[8], addrC[8], addrD[8], idxP[8];
    #pragma unroll
    for (int r = 0; r < 8; ++r) {
        addrB[r]  = swz14((lane & 7) + 8 * r + 64 * (lane >> 3) + 512 * wave);
        // trip2 gather from trip2's contiguous (owner-major) image:
        // amp j at 512*j[11:9] + 64*j[8:6] + 8*j[2:0] + j[5:3]
        addrC2[r] = swz14(512 * wave + 64 * r + 8 * (lane & 7) + (lane >> 3));
        addrC[r]  = swz14(lane + 64 * r + 512 * wave);   // trip3 dump (p=j)
        int jD    = lane + 64 * wave + 512 * r;
        addrD[r]  = swz14(jD);
        int b0 = (jD >> 11) & 1;
        int pref = b0, outv = 0;
        for (int w = 1; w < NQ; ++w) {
            pref ^= (jD >> (11 - w)) & 1;
            outv |= pref << (11 - w);
        }
        outv |= (b0 ^ pref) << 11;
        idxP[r] = swz14(outv);
    }

    f2 a[8];
    #pragma unroll
    for (int r = 0; r < 8; ++r) a[r] = (f2){0.f, 0.f};
    if (tid == 0) a[0].x = 1.f;
    __syncthreads();   // s_u ready, enc buf reads done

    // ---------------- K steps ----------------
    for (int k = 0; k < KS; ++k) {
        // preload this step's 12 gate coefficient quads (b128 broadcasts)
        float4 cf[NQ];
        #pragma unroll
        for (int w = 0; w < NQ; ++w) cf[w] = *(const float4*)&s_u[k][w][0];

        // phase 1 (L_A): wires 11,10,9
        RG(0, 11) RG(1, 10) RG(2, 9)

        // trip 1 (intra-wave): b128 dump -> gather L_B (HW in-order DS)
        #pragma unroll
        for (int i = 0; i < 4; ++i)
            ((float4*)buf0)[baseA4 ^ i] =
                make_float4(a[2*i].x, a[2*i].y, a[2*i+1].x, a[2*i+1].y);
        WAVE_FENCE();
        #pragma unroll
        for (int r = 0; r < 8; ++r) a[r] = buf0[addrB[r]];

        // phase 2 (L_B): wires 8,7,6
        RG(0, 8) RG(1, 7) RG(2, 6)

        // trip 2 (intra-wave): CONTIGUOUS b128 dump -> gather L_C (addrC2)
        #pragma unroll
        for (int i = 0; i < 4; ++i)
            ((float4*)buf0)[baseA4 ^ i] =
                make_float4(a[2*i].x, a[2*i].y, a[2*i+1].x, a[2*i+1].y);
        WAVE_FENCE();
        #pragma unroll
        for (int r = 0; r < 8; ++r) a[r] = buf0[addrC2[r]];

        // phase 3 (L_C): wires 5,4,3
        RG(0, 5) RG(1, 4) RG(2, 3)

        // trip 3 (cross-wave): dump L_C (p=j image) -> barrier -> gather L_D
        #pragma unroll
        for (int r = 0; r < 8; ++r) buf0[addrC[r]] = a[r];
        BARRIER();                                         // B1 (lgkm-only)
        #pragma unroll
        for (int r = 0; r < 8; ++r) a[r] = buf0[addrD[r]];

        // phase 4 (L_D): wires 2,1,0
        RG(0, 2) RG(1, 1) RG(2, 0)

        // trip 4: ring scatter (feeds NEXT step only -- skip on last step)
        if (k < KS - 1) {
            #pragma unroll
            for (int r = 0; r < 8; ++r) buf1[idxP[r]] = a[r];
        }

        // Walsh partials -> single b128 (expvals deferred to epilogue)
        {
            float p[8];
            #pragma unroll
            for (int r = 0; r < 8; ++r)
                p[r] = a[r].x * a[r].x + a[r].y * a[r].y;
            float Q1 = (p[0]+p[1]+p[6]+p[7]) - (p[2]+p[3]+p[4]+p[5]);
            float Q2 = (p[0]+p[3]+p[5]+p[6]) - (p[1]+p[2]+p[4]+p[7]);
            float Q0 = (p[0]+p[3]+p[4]+p[7]) - (p[1]+p[2]+p[5]+p[6]);
            *(float4*)&s_pq[k][tid][0] = make_float4(Q0, Q1, Q2, 0.f);
        }

        if (k < KS - 1) {
            BARRIER();                                     // B2 (lgkm-only)
            #pragma unroll
            for (int i = 0; i < 4; ++i) {
                float4 v = ((float4*)buf1)[baseA4 ^ i];
                a[2*i]   = (f2){v.x, v.y};
                a[2*i+1] = (f2){v.z, v.w};
            }
        }
    }

    // ---------------- epilogue: one-shot Walsh reductions ----------------
    BARRIER();   // s_pq complete (also fences step-5 partials)
    if (wave < KS) {
        int k = wave;
        // fold original-wave (j[8:6]) signs at load time (linearity)
        float sA = 0.f, sB0 = 0.f, sB1 = 0.f, sB2 = 0.f, sB3 = 0.f, sC = 0.f;
        #pragma unroll
        for (int w2 = 0; w2 < 8; ++w2) {
            float4 Qv = *(const float4*)&s_pq[k][(w2 << 6) | lane][0];
            float Q0v = Qv.x, Q1v = Qv.y, Q2v = Qv.z;
            int w2b_  = (w2 >> 2) & 1;
            int w12_  = ((w2 >> 1) ^ (w2 >> 2)) & 1;
            int wall_ = (w2 ^ (w2 >> 1) ^ (w2 >> 2)) & 1;
            sA  += Q1v;
            sB0 += Q2v;
            sB1 += w2b_  ? -Q2v : Q2v;
            sB2 += w12_  ? -Q2v : Q2v;
            sB3 += wall_ ? -Q2v : Q2v;
            sC  += wall_ ? -Q0v : Q0v;
        }
        // plain allreduces: wires 1..5
        float v5s = sB3;
        BF_PLAIN(sA,32)  BF_PLAIN(sA,16)  BF_PLAIN(sA,8)
        BF_PLAIN(sA,4)   BF_PLAIN(sA,2)   BF_PLAIN(sA,1)
        BF_PLAIN(sB0,32) BF_PLAIN(sB0,16) BF_PLAIN(sB0,8)
        BF_PLAIN(sB0,4)  BF_PLAIN(sB0,2)  BF_PLAIN(sB0,1)
        BF_PLAIN(sB1,32) BF_PLAIN(sB1,16) BF_PLAIN(sB1,8)
        BF_PLAIN(sB1,4)  BF_PLAIN(sB1,2)  BF_PLAIN(sB1,1)
        BF_PLAIN(sB2,32) BF_PLAIN(sB2,16) BF_PLAIN(sB2,8)
        BF_PLAIN(sB2,4)  BF_PLAIN(sB2,2)  BF_PLAIN(sB2,1)
        BF_PLAIN(v5s,32) BF_PLAIN(v5s,16) BF_PLAIN(v5s,8)
        BF_PLAIN(v5s,4)  BF_PLAIN(v5s,2)  BF_PLAIN(v5s,1)
        // wire 0: full lane-parity chain on sC
        BF_SIGN(sC,32) BF_SIGN(sC,16) BF_SIGN(sC,8)
        BF_SIGN(sC,4)  BF_SIGN(sC,2)  BF_SIGN(sC,1)
        // wires 6..11: c-chain partial parities on sB3
        float c = sB3;
        BF_SIGN(c,32);
        float w6v = c; BF_PLAIN(w6v,16) BF_PLAIN(w6v,8) BF_PLAIN(w6v,4)
                       BF_PLAIN(w6v,2)  BF_PLAIN(w6v,1)
        BF_SIGN(c,16);
        float w7v = c; BF_PLAIN(w7v,8) BF_PLAIN(w7v,4)
                       BF_PLAIN(w7v,2) BF_PLAIN(w7v,1)
        BF_SIGN(c,8);
        float w8v = c; BF_PLAIN(w8v,4) BF_PLAIN(w8v,2) BF_PLAIN(w8v,1)
        BF_SIGN(c,4);
        float w9v = c; BF_PLAIN(w9v,2) BF_PLAIN(w9v,1)
        BF_SIGN(c,2);
        float w10v = c; BF_PLAIN(w10v,1)
        BF_SIGN(c,1);
        if (lane == 0) {
            s_rall[k][0]  = sC;
            s_rall[k][1]  = sA;
            s_rall[k][2]  = sB0;
            s_rall[k][3]  = sB1;
            s_rall[k][4]  = sB2;
            s_rall[k][5]  = v5s;
            s_rall[k][6]  = w6v;
            s_rall[k][7]  = w7v;
            s_rall[k][8]  = w8v;
            s_rall[k][9]  = w9v;
            s_rall[k][10] = w10v;
            s_rall[k][11] = c;
        }
    }

    // ---------------- final stores (v7 verbatim) ----------------
    BARRIER();   // s_rall complete, visible to all waves
    if (tid < KS * NQ) {                       // 72 threads: readouts
        int k = tid / NQ, i = tid - k * NQ;
        readouts[(k * BB + b) * NQ + i] = s_rall[k][i];
    }
    if (tid >= 128 && tid < 128 + KS * 8) {    // wave 2: logits + last
        int t = tid - 128;
        int k = t >> 3, c = t & 7;
        float acc2 = s_hb[c];
        #pragma unroll
        for (int i = 0; i < NQ; ++i)
            acc2 = fmaf(s_rall[k][i], s_hw[c * NQ + i], acc2);
        logits[(k * BB + b) * 8 + c] = acc2;
        if (k == KS - 1) last[b * 8 + c] = acc2;
    }
}

extern "C" void kernel_launch(void* const* d_in, const int* in_sizes, int n_in,
                              void* d_out, int out_size, void* d_ws, size_t ws_size,
                              hipStream_t stream) {
    const int*   ids   = (const int*)d_in[0];
    const int*   mask  = (const int*)d_in[1];
    const float* emb   = (const float*)d_in[2];
    const float* pw    = (const float*)d_in[3];
    const float* pb    = (const float*)d_in[4];
    const float* theta = (const float*)d_in[5];
    const float* hw    = (const float*)d_in[6];
    const float* hb    = (const float*)d_in[7];
    float* out = (float*)d_out;

    float* readouts = out + KS * BB * 8;              // [K,B,NQ]
    float* last     = out + KS * BB * 8 + KS * BB * NQ;

    fused_kernel<<<BB, 512, 0, stream>>>(ids, mask, emb, pw, pb, theta,
                                         hw, hb, readouts, out, last);
}